// Round 7
// baseline (401.288 us; speedup 1.0000x reference)
//
#include <hip/hip_runtime.h>

#define S_LEN 2048
#define HID   2048
#define NHEAD 16
#define HDIM  128
#define BATCH 2
#define KDIM  2048

using bf16x8  = __attribute__((ext_vector_type(8))) short;
using f32x4   = __attribute__((ext_vector_type(4))) float;
using short4v = __attribute__((ext_vector_type(4))) short;

__device__ __forceinline__ short f2bf(float f) {
  union { float f; unsigned u; } v; v.f = f;
  unsigned r = v.u + 0x7fffu + ((v.u >> 16) & 1u);
  return (short)(r >> 16);
}
__device__ __forceinline__ float bf2f(short s) {
  union { unsigned u; float f; } v;
  v.u = ((unsigned)(unsigned short)s) << 16;
  return v.f;
}

// async global->LDS, 16B per lane. LDS dest must be wave-uniform base + lane*16.
__device__ __forceinline__ void gl_lds16(const void* g, void* l) {
  __builtin_amdgcn_global_load_lds(
      (const __attribute__((address_space(1))) void*)g,
      (__attribute__((address_space(3))) void*)l, 16, 0, 0);
}

// ---------------- convert: hs, wq, wk, wv, wo  f32 -> bf16 -------------------
__global__ __launch_bounds__(256)
void convert_all(const float* __restrict__ hs, const float* __restrict__ wq,
                 const float* __restrict__ wk, const float* __restrict__ wv,
                 const float* __restrict__ wo,
                 short* __restrict__ hsb, short* __restrict__ wqkv,
                 short* __restrict__ wob)
{
  int i = blockIdx.x * 256 + threadIdx.x;
  const float* src; short* dst; int j = i;
  if (j < 1048576)      { src = hs; dst = hsb; }
  else if (j < 1572864) { j -= 1048576; src = wq; dst = wqkv; }
  else if (j < 2097152) { j -= 1572864; src = wk; dst = wqkv + 4194304; }
  else if (j < 2621440) { j -= 2097152; src = wv; dst = wqkv + 8388608; }
  else                  { j -= 2621440; src = wo; dst = wob; }
  f32x4 a = ((const f32x4*)src)[2 * j];
  f32x4 b = ((const f32x4*)src)[2 * j + 1];
  bf16x8 o;
  o[0]=f2bf(a[0]); o[1]=f2bf(a[1]); o[2]=f2bf(a[2]); o[3]=f2bf(a[3]);
  o[4]=f2bf(b[0]); o[5]=f2bf(b[1]); o[6]=f2bf(b[2]); o[7]=f2bf(b[3]);
  ((bf16x8*)dst)[j] = o;
}

// ---------------- bf16 GEMM, C = A @ B^T + bias (m97 structure) --------------
template<int KIND>
__global__ __launch_bounds__(256)
void gemm128(const short* __restrict__ A, const short* __restrict__ B,
             const float* __restrict__ bias0, const float* __restrict__ bias1,
             const float* __restrict__ bias2,
             void* __restrict__ O0, void* __restrict__ O1, void* __restrict__ O2)
{
  __shared__ __align__(16) short As[128 * 32];
  __shared__ __align__(16) short Bs[128 * 32];
  const int tid  = threadIdx.x;
  const int lane = tid & 63, wave = tid >> 6;
  const int ln = lane & 15, g = lane >> 4;
  const int wr = wave >> 1, wc = wave & 1;
  const int m0 = blockIdx.x * 128, n0 = blockIdx.y * 128;

  const int c0 = tid, c1 = tid + 256;
  const short* aP0 = A + (size_t)(m0 + (c0 >> 2)) * KDIM + (c0 & 3) * 8;
  const short* aP1 = A + (size_t)(m0 + (c1 >> 2)) * KDIM + (c1 & 3) * 8;
  const short* bP0 = B + (size_t)(n0 + (c0 >> 2)) * KDIM + (c0 & 3) * 8;
  const short* bP1 = B + (size_t)(n0 + (c1 >> 2)) * KDIM + (c1 & 3) * 8;

  f32x4 acc[4][4] = {};

  for (int k0 = 0; k0 < KDIM; k0 += 32) {
    __syncthreads();
    gl_lds16(aP0 + k0, &As[c0 * 8]);
    gl_lds16(aP1 + k0, &As[c1 * 8]);
    gl_lds16(bP0 + k0, &Bs[c0 * 8]);
    gl_lds16(bP1 + k0, &Bs[c1 * 8]);
    __syncthreads();

    bf16x8 af[4], bfm[4];
#pragma unroll
    for (int i = 0; i < 4; ++i)
      af[i] = *(const bf16x8*)&As[(wr * 64 + i * 16 + ln) * 32 + g * 8];
#pragma unroll
    for (int j = 0; j < 4; ++j)
      bfm[j] = *(const bf16x8*)&Bs[(wc * 64 + j * 16 + ln) * 32 + g * 8];
#pragma unroll
    for (int i = 0; i < 4; ++i)
#pragma unroll
      for (int j = 0; j < 4; ++j)
        acc[i][j] = __builtin_amdgcn_mfma_f32_16x16x32_bf16(af[i], bfm[j], acc[i][j], 0, 0, 0);
  }

  if constexpr (KIND == 0) {
    const int seg   = n0 >> 11;
    const int nbase = (n0 & 2047) + wc * 64;
    const float* bias = (seg == 0) ? bias0 : (seg == 1) ? bias1 : bias2;
    float bvv[4];
#pragma unroll
    for (int j = 0; j < 4; ++j) bvv[j] = bias[nbase + j * 16 + ln];
    if (seg < 2) {           // Q,K -> [b][h][s][d] bf16
      short* C = (short*)(seg ? O1 : O0);
#pragma unroll
      for (int i = 0; i < 4; ++i) {
        const int mb = m0 + wr * 64 + i * 16 + 4 * g;
#pragma unroll
        for (int j = 0; j < 4; ++j) {
          const int nl = nbase + j * 16 + ln;
          const int h = nl >> 7, d = nl & 127;
#pragma unroll
          for (int e = 0; e < 4; ++e) {
            const int m = mb + e, bb = m >> 11, t = m & (S_LEN - 1);
            C[((size_t)((bb * NHEAD + h) * S_LEN + t) << 7) + d] = f2bf(acc[i][j][e] + bvv[j]);
          }
        }
      }
    } else {                 // V -> transposed [b][h][d][s] bf16
      short* C = (short*)O2;
#pragma unroll
      for (int i = 0; i < 4; ++i) {
        const int mb = m0 + wr * 64 + i * 16 + 4 * g;
        const int bb = mb >> 11, t0 = mb & (S_LEN - 1);
#pragma unroll
        for (int j = 0; j < 4; ++j) {
          const int nl = nbase + j * 16 + ln;
          const int h = nl >> 7, d = nl & 127;
          short4v v;
#pragma unroll
          for (int e = 0; e < 4; ++e) v[e] = f2bf(acc[i][j][e] + bvv[j]);
          *(short4v*)&C[((size_t)((bb * NHEAD + h) * HDIM + d)) * S_LEN + t0] = v;
        }
      }
    }
  } else {                   // O-proj -> f32
    float* C = (float*)O0;
    float bvv[4];
#pragma unroll
    for (int j = 0; j < 4; ++j) bvv[j] = bias0[n0 + wc * 64 + j * 16 + ln];
#pragma unroll
    for (int i = 0; i < 4; ++i) {
      const int mb = m0 + wr * 64 + i * 16 + 4 * g;
#pragma unroll
      for (int j = 0; j < 4; ++j) {
        const int n = n0 + wc * 64 + j * 16 + ln;
#pragma unroll
        for (int e = 0; e < 4; ++e)
          C[(size_t)(mb + e) * HID + n] = acc[i][j][e] + bvv[j];
      }
    }
  }
}

// ---------------- RoPE in-place on Q,K ([b][h][s][d] bf16) -------------------
// Q additionally pre-scaled by 1/sqrt(HD)*log2(e): softmax runs in exp2 domain.
#define QSCALE 0.12752767502f   // (1/sqrt(128)) * log2(e)
__global__ __launch_bounds__(256)
void rope_kernel(short* __restrict__ Qb, short* __restrict__ Kb,
                 const int* __restrict__ pos_ids)
{
  const int row = blockIdx.x * 4 + (threadIdx.x >> 6);
  const int d   = threadIdx.x & 63;
  const int bh  = row >> 11, t = row & (S_LEN - 1);
  const int b   = bh >> 4;
  const float pos = (float)pos_ids[b * S_LEN + t];
  const float inv = powf(10000.0f, -(float)d * (1.0f / 64.0f));
  float s, c;
  sincosf(pos * inv, &s, &c);
  const size_t base = (size_t)row * HDIM;
  {
    float x1 = bf2f(Qb[base + d]), x2 = bf2f(Qb[base + d + 64]);
    Qb[base + d]      = f2bf((x1 * c - x2 * s) * QSCALE);
    Qb[base + d + 64] = f2bf((x2 * c + x1 * s) * QSCALE);
  }
  {
    float x1 = bf2f(Kb[base + d]), x2 = bf2f(Kb[base + d + 64]);
    Kb[base + d]      = f2bf(x1 * c - x2 * s);
    Kb[base + d + 64] = f2bf(x2 * c + x1 * s);
  }
}

// ---------------- flash attention -------------------------------------------
// ROUND-1 register structure (116 VGPR, 4 blocks/CU) + zero-state VALU diets:
// reg-staged K/V (NOT gl_lds: per-lane 64b src addrs cost ~25 VGPR), exp2
// softmax, diag-only mask, distributed l, balanced 1D grid, wave-local P sync.
__global__ __launch_bounds__(256)
void attn_kernel(const short* __restrict__ Qb, const short* __restrict__ Kb,
                 const short* __restrict__ Vt, short* __restrict__ AO)
{
  __shared__ __align__(16) short Ks[64 * 128];
  __shared__ __align__(16) short Vs[128 * 64];
  __shared__ __align__(16) short Ps[4][16 * 64];
  const int tid = threadIdx.x, wave = tid >> 6, lane = tid & 63;
  const int ln = lane & 15, g = lane >> 4;
  const int bid = blockIdx.x;
  const int bh  = bid & 31;
  const int grp = bid >> 5;
  const int yt  = (grp & 1) ? (31 - (grp >> 1)) : (grp >> 1);
  const int qw  = yt * 64 + wave * 16;

  bf16x8 qf[4];
#pragma unroll
  for (int ks = 0; ks < 4; ++ks)
    qf[ks] = *(const bf16x8*)&Qb[((size_t)bh * S_LEN + qw + ln) * HDIM + ks * 32 + g * 8];

  f32x4 o[8] = {};
  float m_e[4], l_e[4];
#pragma unroll
  for (int e = 0; e < 4; ++e) { m_e[e] = -3.0e38f; l_e[e] = 0.f; }

  for (int kvt = 0; kvt <= yt; ++kvt) {
    const int kv0 = kvt * 64;
    __syncthreads();
#pragma unroll
    for (int p = 0; p < 4; ++p) {
      const int gi = tid + p * 256;
      {  // K tile [64][128], row-XOR-swizzled
        const int row = gi >> 4, c8 = gi & 15;
        bf16x8 v = *(const bf16x8*)&Kb[((size_t)bh * S_LEN + kv0 + row) * HDIM + c8 * 8];
        *(bf16x8*)&Ks[(row * 128 + c8 * 8) ^ ((row & 7) << 3)] = v;
      }
      {  // V tile as [d=128][kv=64]
        const int dr = gi >> 3, cg = gi & 7;
        bf16x8 v = *(const bf16x8*)&Vt[((size_t)bh * HDIM + dr) * S_LEN + kv0 + cg * 8];
        *(bf16x8*)&Vs[(dr * 64 + cg * 8) ^ ((dr & 7) << 3)] = v;
      }
    }
    __syncthreads();

    // S = Q K^T  (exp2 domain: Q carries scale*log2e)
    f32x4 sfr[4] = {};
#pragma unroll
    for (int ks = 0; ks < 4; ++ks) {
#pragma unroll
      for (int nt = 0; nt < 4; ++nt) {
        const int row = nt * 16 + ln;
        bf16x8 kf = *(const bf16x8*)&Ks[(row * 128 + ks * 32 + g * 8) ^ ((ln & 7) << 3)];
        sfr[nt] = __builtin_amdgcn_mfma_f32_16x16x32_bf16(qf[ks], kf, sfr[nt], 0, 0, 0);
      }
    }

    // online softmax (exp2); mask only diagonal tile; distributed l.
    const bool diag = (kvt == yt);
#pragma unroll
    for (int e = 0; e < 4; ++e) {
      const int q = qw + 4 * g + e;
      if (diag) {
#pragma unroll
        for (int nt = 0; nt < 4; ++nt)
          if (kv0 + nt * 16 + ln > q) sfr[nt][e] = -3.0e38f;
      }
      float rmax = fmaxf(fmaxf(sfr[0][e], sfr[1][e]), fmaxf(sfr[2][e], sfr[3][e]));
#pragma unroll
      for (int msk = 1; msk < 16; msk <<= 1)
        rmax = fmaxf(rmax, __shfl_xor(rmax, msk));
      if (rmax > m_e[e]) {
        const float corr = exp2f(m_e[e] - rmax);
        m_e[e] = rmax;
        l_e[e] *= corr;
#pragma unroll
        for (int nt2 = 0; nt2 < 8; ++nt2) o[nt2][e] *= corr;
      }
      float psum = 0.f;
#pragma unroll
      for (int nt = 0; nt < 4; ++nt) {
        const float pv = exp2f(sfr[nt][e] - m_e[e]);
        sfr[nt][e] = pv;
        psum += pv;
      }
      l_e[e] += psum;   // lane-local partial; reduced once at epilogue
    }

    // P -> per-wave LDS (C-layout -> A-layout), swizzled
    short* pw = &Ps[wave][0];
#pragma unroll
    for (int e = 0; e < 4; ++e) {
      const int r = 4 * g + e;
#pragma unroll
      for (int nt = 0; nt < 4; ++nt) {
        const int cc = nt * 16 + ln;
        pw[(r * 64 + cc) ^ ((r & 7) << 3)] = f2bf(sfr[nt][e]);
      }
    }
    // Ps is per-wave: wave-local LDS ordering suffices (no block barrier)
    asm volatile("s_waitcnt lgkmcnt(0)" ::: "memory");
    __builtin_amdgcn_sched_barrier(0);

    // O += P V
#pragma unroll
    for (int ks2 = 0; ks2 < 2; ++ks2) {
      bf16x8 pa = *(const bf16x8*)&pw[(ln * 64 + ks2 * 32 + g * 8) ^ ((ln & 7) << 3)];
#pragma unroll
      for (int nt2 = 0; nt2 < 8; ++nt2) {
        const int row = nt2 * 16 + ln;
        bf16x8 vb = *(const bf16x8*)&Vs[(row * 64 + ks2 * 32 + g * 8) ^ ((ln & 7) << 3)];
        o[nt2] = __builtin_amdgcn_mfma_f32_16x16x32_bf16(pa, vb, o[nt2], 0, 0, 0);
      }
    }
  }

  // epilogue: reduce l across the 16 lanes of each row, normalize, write
  const int b = bh >> 4, h = bh & 15;
#pragma unroll
  for (int e = 0; e < 4; ++e) {
    float l = l_e[e];
#pragma unroll
    for (int msk = 1; msk < 16; msk <<= 1)
      l += __shfl_xor(l, msk);
    const float inv = 1.0f / l;
    const int q = qw + 4 * g + e;
    short* dst = &AO[((size_t)b * S_LEN + q) * HID + h * HDIM];
#pragma unroll
    for (int nt2 = 0; nt2 < 8; ++nt2)
      dst[nt2 * 16 + ln] = f2bf(o[nt2][e] * inv);
  }
}

extern "C" void kernel_launch(void* const* d_in, const int* in_sizes, int n_in,
                              void* d_out, int out_size, void* d_ws, size_t ws_size,
                              hipStream_t stream)
{
  const float* hs = (const float*)d_in[0];
  const float* wq = (const float*)d_in[1];
  const float* bq = (const float*)d_in[2];
  const float* wk = (const float*)d_in[3];
  const float* bk = (const float*)d_in[4];
  const float* wv = (const float*)d_in[5];
  const float* bv = (const float*)d_in[6];
  const float* wo = (const float*)d_in[7];
  const float* bo = (const float*)d_in[8];
  const int*  pos = (const int*)d_in[10];
  float* out = (float*)d_out;

  const size_t TSZ = (size_t)BATCH * NHEAD * S_LEN * HDIM;  // 8388608 elems
  short* Qb   = (short*)d_ws;
  short* Kb   = Qb + TSZ;
  short* Vt   = Kb + TSZ;
  short* hsb  = Vt + TSZ;        // hs bf16; reused as AO after QKV GEMM
  short* AO   = hsb;
  short* Wqkv = hsb + TSZ;
  short* wob  = Wqkv + 12582912;

  convert_all<<<12288, 256, 0, stream>>>(hs, wq, wk, wv, wo, hsb, Wqkv, wob);
  gemm128<0><<<dim3(32, 48), 256, 0, stream>>>(hsb, Wqkv, bq, bk, bv, Qb, Kb, Vt);
  rope_kernel<<<(BATCH * NHEAD * S_LEN) / 4, 256, 0, stream>>>(Qb, Kb, pos);
  attn_kernel<<<1024, 256, 0, stream>>>(Qb, Kb, Vt, AO);
  gemm128<1><<<dim3(32, 16), 256, 0, stream>>>(AO, wob, bo, nullptr, nullptr, out, nullptr, nullptr);
}

// Round 8
// 325.942 us; speedup vs baseline: 1.2312x; 1.2312x over previous
//
#include <hip/hip_runtime.h>

#define S_LEN 2048
#define HID   2048
#define NHEAD 16
#define HDIM  128
#define BATCH 2
#define KDIM  2048

using bf16x8  = __attribute__((ext_vector_type(8))) short;
using f32x4   = __attribute__((ext_vector_type(4))) float;
using short4v = __attribute__((ext_vector_type(4))) short;

__device__ __forceinline__ short f2bf(float f) {
  union { float f; unsigned u; } v; v.f = f;
  unsigned r = v.u + 0x7fffu + ((v.u >> 16) & 1u);
  return (short)(r >> 16);
}
__device__ __forceinline__ float bf2f(short s) {
  union { unsigned u; float f; } v;
  v.u = ((unsigned)(unsigned short)s) << 16;
  return v.f;
}

// async global->LDS, 16B per lane. LDS dest must be wave-uniform base + lane*16.
__device__ __forceinline__ void gl_lds16(const void* g, void* l) {
  __builtin_amdgcn_global_load_lds(
      (const __attribute__((address_space(1))) void*)g,
      (__attribute__((address_space(3))) void*)l, 16, 0, 0);
}

// ---------------- convert: hs, wq, wk, wv, wo  f32 -> bf16 -------------------
__global__ __launch_bounds__(256)
void convert_all(const float* __restrict__ hs, const float* __restrict__ wq,
                 const float* __restrict__ wk, const float* __restrict__ wv,
                 const float* __restrict__ wo,
                 short* __restrict__ hsb, short* __restrict__ wqkv,
                 short* __restrict__ wob)
{
  int i = blockIdx.x * 256 + threadIdx.x;
  const float* src; short* dst; int j = i;
  if (j < 1048576)      { src = hs; dst = hsb; }
  else if (j < 1572864) { j -= 1048576; src = wq; dst = wqkv; }
  else if (j < 2097152) { j -= 1572864; src = wk; dst = wqkv + 4194304; }
  else if (j < 2621440) { j -= 2097152; src = wv; dst = wqkv + 8388608; }
  else                  { j -= 2621440; src = wo; dst = wob; }
  f32x4 a = ((const f32x4*)src)[2 * j];
  f32x4 b = ((const f32x4*)src)[2 * j + 1];
  bf16x8 o;
  o[0]=f2bf(a[0]); o[1]=f2bf(a[1]); o[2]=f2bf(a[2]); o[3]=f2bf(a[3]);
  o[4]=f2bf(b[0]); o[5]=f2bf(b[1]); o[6]=f2bf(b[2]); o[7]=f2bf(b[3]);
  ((bf16x8*)dst)[j] = o;
}

// ---------------- bf16 GEMM, C = A @ B^T + bias (m97 structure) --------------
template<int KIND>
__global__ __launch_bounds__(256)
void gemm128(const short* __restrict__ A, const short* __restrict__ B,
             const float* __restrict__ bias0, const float* __restrict__ bias1,
             const float* __restrict__ bias2,
             void* __restrict__ O0, void* __restrict__ O1, void* __restrict__ O2)
{
  __shared__ __align__(16) short As[128 * 32];
  __shared__ __align__(16) short Bs[128 * 32];
  const int tid  = threadIdx.x;
  const int lane = tid & 63, wave = tid >> 6;
  const int ln = lane & 15, g = lane >> 4;
  const int wr = wave >> 1, wc = wave & 1;
  const int m0 = blockIdx.x * 128, n0 = blockIdx.y * 128;

  const int c0 = tid, c1 = tid + 256;
  const short* aP0 = A + (size_t)(m0 + (c0 >> 2)) * KDIM + (c0 & 3) * 8;
  const short* aP1 = A + (size_t)(m0 + (c1 >> 2)) * KDIM + (c1 & 3) * 8;
  const short* bP0 = B + (size_t)(n0 + (c0 >> 2)) * KDIM + (c0 & 3) * 8;
  const short* bP1 = B + (size_t)(n0 + (c1 >> 2)) * KDIM + (c1 & 3) * 8;

  f32x4 acc[4][4] = {};

  for (int k0 = 0; k0 < KDIM; k0 += 32) {
    __syncthreads();
    gl_lds16(aP0 + k0, &As[c0 * 8]);
    gl_lds16(aP1 + k0, &As[c1 * 8]);
    gl_lds16(bP0 + k0, &Bs[c0 * 8]);
    gl_lds16(bP1 + k0, &Bs[c1 * 8]);
    __syncthreads();

    bf16x8 af[4], bfm[4];
#pragma unroll
    for (int i = 0; i < 4; ++i)
      af[i] = *(const bf16x8*)&As[(wr * 64 + i * 16 + ln) * 32 + g * 8];
#pragma unroll
    for (int j = 0; j < 4; ++j)
      bfm[j] = *(const bf16x8*)&Bs[(wc * 64 + j * 16 + ln) * 32 + g * 8];
#pragma unroll
    for (int i = 0; i < 4; ++i)
#pragma unroll
      for (int j = 0; j < 4; ++j)
        acc[i][j] = __builtin_amdgcn_mfma_f32_16x16x32_bf16(af[i], bfm[j], acc[i][j], 0, 0, 0);
  }

  if constexpr (KIND == 0) {
    const int seg   = n0 >> 11;
    const int nbase = (n0 & 2047) + wc * 64;
    const float* bias = (seg == 0) ? bias0 : (seg == 1) ? bias1 : bias2;
    float bvv[4];
#pragma unroll
    for (int j = 0; j < 4; ++j) bvv[j] = bias[nbase + j * 16 + ln];
    if (seg < 2) {           // Q,K -> [b][h][s][d] bf16
      short* C = (short*)(seg ? O1 : O0);
#pragma unroll
      for (int i = 0; i < 4; ++i) {
        const int mb = m0 + wr * 64 + i * 16 + 4 * g;
#pragma unroll
        for (int j = 0; j < 4; ++j) {
          const int nl = nbase + j * 16 + ln;
          const int h = nl >> 7, d = nl & 127;
#pragma unroll
          for (int e = 0; e < 4; ++e) {
            const int m = mb + e, bb = m >> 11, t = m & (S_LEN - 1);
            C[((size_t)((bb * NHEAD + h) * S_LEN + t) << 7) + d] = f2bf(acc[i][j][e] + bvv[j]);
          }
        }
      }
    } else {                 // V -> transposed [b][h][d][s] bf16
      short* C = (short*)O2;
#pragma unroll
      for (int i = 0; i < 4; ++i) {
        const int mb = m0 + wr * 64 + i * 16 + 4 * g;
        const int bb = mb >> 11, t0 = mb & (S_LEN - 1);
#pragma unroll
        for (int j = 0; j < 4; ++j) {
          const int nl = nbase + j * 16 + ln;
          const int h = nl >> 7, d = nl & 127;
          short4v v;
#pragma unroll
          for (int e = 0; e < 4; ++e) v[e] = f2bf(acc[i][j][e] + bvv[j]);
          *(short4v*)&C[((size_t)((bb * NHEAD + h) * HDIM + d)) * S_LEN + t0] = v;
        }
      }
    }
  } else {                   // O-proj -> f32
    float* C = (float*)O0;
    float bvv[4];
#pragma unroll
    for (int j = 0; j < 4; ++j) bvv[j] = bias0[n0 + wc * 64 + j * 16 + ln];
#pragma unroll
    for (int i = 0; i < 4; ++i) {
      const int mb = m0 + wr * 64 + i * 16 + 4 * g;
#pragma unroll
      for (int j = 0; j < 4; ++j) {
        const int n = n0 + wc * 64 + j * 16 + ln;
#pragma unroll
        for (int e = 0; e < 4; ++e)
          C[(size_t)(mb + e) * HID + n] = acc[i][j][e] + bvv[j];
      }
    }
  }
}

// ---------------- RoPE in-place on Q,K ([b][h][s][d] bf16) -------------------
// Q additionally pre-scaled by 1/sqrt(HD)*log2(e): softmax runs in exp2 domain.
#define QSCALE 0.12752767502f   // (1/sqrt(128)) * log2(e)
__global__ __launch_bounds__(256)
void rope_kernel(short* __restrict__ Qb, short* __restrict__ Kb,
                 const int* __restrict__ pos_ids)
{
  const int row = blockIdx.x * 4 + (threadIdx.x >> 6);
  const int d   = threadIdx.x & 63;
  const int bh  = row >> 11, t = row & (S_LEN - 1);
  const int b   = bh >> 4;
  const float pos = (float)pos_ids[b * S_LEN + t];
  const float inv = powf(10000.0f, -(float)d * (1.0f / 64.0f));
  float s, c;
  sincosf(pos * inv, &s, &c);
  const size_t base = (size_t)row * HDIM;
  {
    float x1 = bf2f(Qb[base + d]), x2 = bf2f(Qb[base + d + 64]);
    Qb[base + d]      = f2bf((x1 * c - x2 * s) * QSCALE);
    Qb[base + d + 64] = f2bf((x2 * c + x1 * s) * QSCALE);
  }
  {
    float x1 = bf2f(Kb[base + d]), x2 = bf2f(Kb[base + d + 64]);
    Kb[base + d]      = f2bf(x1 * c - x2 * s);
    Kb[base + d + 64] = f2bf(x2 * c + x1 * s);
  }
}

// ---------------- flash attention -------------------------------------------
// EXACT round-1 register structure (measured 116 VGPR, 4 blocks/CU, 132 us).
// Only register-neutral diffs: (a) 1D balanced grid (index math), (b) exp2
// softmax w/ Q pre-scaled (REMOVES one mul), (c) lane-local l partial sums
// (REMOVES 16 shfls/iter). Mask always-on, rescale unconditional,
// __syncthreads for P -- all as round 1.
__global__ __launch_bounds__(256)
void attn_kernel(const short* __restrict__ Qb, const short* __restrict__ Kb,
                 const short* __restrict__ Vt, short* __restrict__ AO)
{
  __shared__ __align__(16) short Ks[64 * 128];
  __shared__ __align__(16) short Vs[128 * 64];
  __shared__ __align__(16) short Ps[4][16 * 64];
  const int tid  = threadIdx.x;
  const int wave = tid >> 6, lane = tid & 63;
  const int ln = lane & 15, g = lane >> 4;
  const int bid = blockIdx.x;
  const int bh  = bid & 31;
  const int grp = bid >> 5;
  const int yt  = (grp & 1) ? (31 - (grp >> 1)) : (grp >> 1);
  const int qw  = yt * 64 + wave * 16;

  bf16x8 qf[4];
#pragma unroll
  for (int ks = 0; ks < 4; ++ks)
    qf[ks] = *(const bf16x8*)&Qb[((size_t)bh * S_LEN + qw + ln) * HDIM + ks * 32 + g * 8];

  f32x4 o[8] = {};
  float m_e[4], l_e[4];
#pragma unroll
  for (int e = 0; e < 4; ++e) { m_e[e] = -3.0e38f; l_e[e] = 0.f; }

  for (int kvt = 0; kvt <= yt; ++kvt) {
    const int kv0 = kvt * 64;
    __syncthreads();
#pragma unroll
    for (int p = 0; p < 4; ++p) {
      const int gi = tid + p * 256;
      {  // K tile [64][128], row-XOR-swizzled
        const int row = gi >> 4, c8 = gi & 15;
        bf16x8 v = *(const bf16x8*)&Kb[((size_t)bh * S_LEN + kv0 + row) * HDIM + c8 * 8];
        *(bf16x8*)&Ks[(row * 128 + c8 * 8) ^ ((row & 7) << 3)] = v;
      }
      {  // V tile as [d=128][kv=64]
        const int dr = gi >> 3, cg = gi & 7;
        bf16x8 v = *(const bf16x8*)&Vt[((size_t)bh * HDIM + dr) * S_LEN + kv0 + cg * 8];
        *(bf16x8*)&Vs[(dr * 64 + cg * 8) ^ ((dr & 7) << 3)] = v;
      }
    }
    __syncthreads();

    // S = Q K^T  (exp2 domain: Q carries scale*log2e)
    f32x4 sfr[4] = {};
#pragma unroll
    for (int ks = 0; ks < 4; ++ks) {
#pragma unroll
      for (int nt = 0; nt < 4; ++nt) {
        const int row = nt * 16 + ln;
        bf16x8 kf = *(const bf16x8*)&Ks[(row * 128 + ks * 32 + g * 8) ^ ((ln & 7) << 3)];
        sfr[nt] = __builtin_amdgcn_mfma_f32_16x16x32_bf16(qf[ks], kf, sfr[nt], 0, 0, 0);
      }
    }

    // causal mask + online softmax (round-1 structure, exp2 domain)
#pragma unroll
    for (int e = 0; e < 4; ++e) {
      const int q = qw + 4 * g + e;
      float rmax = -3.0e38f;
#pragma unroll
      for (int nt = 0; nt < 4; ++nt) {
        float v = sfr[nt][e];
        if (kv0 + nt * 16 + ln > q) v = -3.0e38f;
        sfr[nt][e] = v;
        rmax = fmaxf(rmax, v);
      }
#pragma unroll
      for (int msk = 1; msk < 16; msk <<= 1)
        rmax = fmaxf(rmax, __shfl_xor(rmax, msk));
      const float mnew = fmaxf(m_e[e], rmax);
      const float corr = exp2f(m_e[e] - mnew);
      m_e[e] = mnew;
      float psum = 0.f;
#pragma unroll
      for (int nt = 0; nt < 4; ++nt) {
        const float pv = exp2f(sfr[nt][e] - mnew);
        sfr[nt][e] = pv;
        psum += pv;
      }
      l_e[e] = l_e[e] * corr + psum;   // lane-local; reduced at epilogue
#pragma unroll
      for (int nt2 = 0; nt2 < 8; ++nt2) o[nt2][e] *= corr;
    }

    // P -> per-wave LDS (C-layout -> A-layout), swizzled
    short* pw = &Ps[wave][0];
#pragma unroll
    for (int e = 0; e < 4; ++e) {
      const int r = 4 * g + e;
#pragma unroll
      for (int nt = 0; nt < 4; ++nt) {
        const int cc = nt * 16 + ln;
        pw[(r * 64 + cc) ^ ((r & 7) << 3)] = f2bf(sfr[nt][e]);
      }
    }
    __syncthreads();  // orders P writes before reads (round-1 idiom)

    // O += P V
#pragma unroll
    for (int ks2 = 0; ks2 < 2; ++ks2) {
      bf16x8 pa = *(const bf16x8*)&pw[(ln * 64 + ks2 * 32 + g * 8) ^ ((ln & 7) << 3)];
#pragma unroll
      for (int nt2 = 0; nt2 < 8; ++nt2) {
        const int row = nt2 * 16 + ln;
        bf16x8 vb = *(const bf16x8*)&Vs[(row * 64 + ks2 * 32 + g * 8) ^ ((ln & 7) << 3)];
        o[nt2] = __builtin_amdgcn_mfma_f32_16x16x32_bf16(pa, vb, o[nt2], 0, 0, 0);
      }
    }
  }

  // epilogue: reduce l across the 16 lanes of each row, normalize, write
  const int b = bh >> 4, h = bh & 15;
#pragma unroll
  for (int e = 0; e < 4; ++e) {
    float l = l_e[e];
#pragma unroll
    for (int msk = 1; msk < 16; msk <<= 1)
      l += __shfl_xor(l, msk);
    const float inv = 1.0f / l;
    const int q = qw + 4 * g + e;
    short* dst = &AO[((size_t)b * S_LEN + q) * HID + h * HDIM];
#pragma unroll
    for (int nt2 = 0; nt2 < 8; ++nt2)
      dst[nt2 * 16 + ln] = f2bf(o[nt2][e] * inv);
  }
}

extern "C" void kernel_launch(void* const* d_in, const int* in_sizes, int n_in,
                              void* d_out, int out_size, void* d_ws, size_t ws_size,
                              hipStream_t stream)
{
  const float* hs = (const float*)d_in[0];
  const float* wq = (const float*)d_in[1];
  const float* bq = (const float*)d_in[2];
  const float* wk = (const float*)d_in[3];
  const float* bk = (const float*)d_in[4];
  const float* wv = (const float*)d_in[5];
  const float* bv = (const float*)d_in[6];
  const float* wo = (const float*)d_in[7];
  const float* bo = (const float*)d_in[8];
  const int*  pos = (const int*)d_in[10];
  float* out = (float*)d_out;

  const size_t TSZ = (size_t)BATCH * NHEAD * S_LEN * HDIM;  // 8388608 elems
  short* Qb   = (short*)d_ws;
  short* Kb   = Qb + TSZ;
  short* Vt   = Kb + TSZ;
  short* hsb  = Vt + TSZ;        // hs bf16; reused as AO after QKV GEMM
  short* AO   = hsb;
  short* Wqkv = hsb + TSZ;
  short* wob  = Wqkv + 12582912;

  convert_all<<<12288, 256, 0, stream>>>(hs, wq, wk, wv, wo, hsb, Wqkv, wob);
  gemm128<0><<<dim3(32, 48), 256, 0, stream>>>(hsb, Wqkv, bq, bk, bv, Qb, Kb, Vt);
  rope_kernel<<<(BATCH * NHEAD * S_LEN) / 4, 256, 0, stream>>>(Qb, Kb, pos);
  attn_kernel<<<1024, 256, 0, stream>>>(Qb, Kb, Vt, AO);
  gemm128<1><<<dim3(32, 16), 256, 0, stream>>>(AO, wob, bo, nullptr, nullptr, out, nullptr, nullptr);
}